// Round 17
// baseline (169.162 us; speedup 1.0000x reference)
//
#include <hip/hip_runtime.h>

// Problem constants (from reference): H=256, N=100000, B=8, S=128 -> T=1024
#define T_ROWS 1024
#define H_DIM  256
#define N_COLS 100000
#define QF     127.0f

#define NB3    782                // ceil(N/128), last block 32 cols
#define TCH    4                  // t-chunks of 256
#define GRID3  (NB3 * TCH)        // 3128 = 8*391 -> bijective XCD swizzle

typedef __attribute__((ext_vector_type(4))) float f32x4;
typedef __attribute__((ext_vector_type(2))) float f32x2;
typedef __attribute__((ext_vector_type(8))) short short8;   // 8 bf16 (MFMA frag)
typedef __attribute__((ext_vector_type(4))) short short4v;  // 4 bf16 = 8B

// Exact f32 -> bf16 for integer-valued floats |q| <= 127: truncation is exact.
__device__ __forceinline__ short f32_to_bf16_exact(float f) {
    unsigned u = __builtin_bit_cast(unsigned, f);
    return (short)(u >> 16);
}

__device__ __forceinline__ float wave_absmax64(float v) {
#pragma unroll
    for (int off = 32; off > 0; off >>= 1)
        v = fmaxf(v, __shfl_xor(v, off, 64));
    return v;
}

// Raw LDS-only barrier: NO vmcnt drain (global stores stay in flight).
// Validated passing in R9/R10/R12/R13/R16.
__device__ __forceinline__ void sync_lds() {
    asm volatile("s_waitcnt lgkmcnt(0)" ::: "memory");
    __builtin_amdgcn_s_barrier();
    __builtin_amdgcn_sched_barrier(0);
}

// ---------------- Kernel 1: quantize X -> FRAG-MAJOR bf16 x8F + absmax
// x8F layout: [tile(32)][kk(8)][mr(2)][lane(64)][j(8)] shorts.
__global__ __launch_bounds__(256) void quant_x(const float* __restrict__ X,
                                               short* __restrict__ x8F,
                                               float* __restrict__ sx) {
    const int w = threadIdx.x >> 6, l = threadIdx.x & 63;
    const int row = blockIdx.x * 4 + w;                 // t
    const float4 v = ((const float4*)X)[row * 64 + l];  // coalesced 16B/lane
    float amax = fmaxf(fmaxf(fabsf(v.x), fabsf(v.y)), fmaxf(fabsf(v.z), fabsf(v.w)));
    amax = wave_absmax64(amax);
    const float scale = (amax == 0.f) ? 1.f : amax;
    const float qs = QF / scale;
    short4v q;
    q.x = f32_to_bf16_exact(rintf(v.x * qs));
    q.y = f32_to_bf16_exact(rintf(v.y * qs));
    q.z = f32_to_bf16_exact(rintf(v.z * qs));
    q.w = f32_to_bf16_exact(rintf(v.w * qs));
    const int tile = row >> 5, mr = (row >> 4) & 1, lm = row & 15;
    const int kk = l >> 3, lg = (l >> 1) & 3, j = (l & 1) * 4;
    const int lane = lg * 16 + lm;
    *(short4v*)(x8F + (((tile * 8 + kk) * 2 + mr) * 64 + lane) * 8 + j) = q;
    if (l == 0) sx[row] = amax;
}

// ---------------- Kernel 2: FUSED W-quantize + GEMM (R13 loop, new prologue)
// Per wave: load its 32 W rows fp32 COALESCED (1 row = 64 lanes x float4 =
// 1KB unit-stride), wave-butterfly row absmax, quantize to bf16 into an
// XOR-swizzled LDS stage (reusing the olds dbuf space -> no extra LDS),
// read B-frags to regs (R1-validated pattern, ~2-way conflicts), row absmax
// -> smax LDS for the store-side dequant. One barrier after the prologue
// protects the LDS union; the R13 loop (lgkm-only barrier, nt full-line
// stores, 3 blocks/CU) is untouched. Removes the quant_w kernel + w8F
// round-trip entirely; W re-reads (4x) are L3-served (W = 102MB < 256MB L3).
__global__ __launch_bounds__(256, 3) void gemm_fused(const short* __restrict__ x8F,
                                                     const float* __restrict__ sx,
                                                     const float* __restrict__ W,
                                                     const float* __restrict__ bias,
                                                     float* __restrict__ out) {
    __shared__ float olds[2][32 * 128];   // 2 x 16KB; prologue reuses as B-stage
    __shared__ float smax[128];           // block-panel W row absmax

    // bijective XCD swizzle (3128 = 8*391); tc-inner -> W panel L2/L3 reuse
    const int bid = blockIdx.x;
    const int s = (bid & 7) * (GRID3 / 8) + (bid >> 3);
    const int nb = s >> 2;                 // 0..781
    const int tc = s & 3;                  // t-chunk of 256 rows
    const int w = threadIdx.x >> 6, l = threadIdx.x & 63;
    const int lg = l >> 4, lm = l & 15;
    const int tbase = tc * 256;
    const float invqq = 1.0f / (QF * QF);

    // ---- fused quantize prologue: wave w stages its 32 rows, 16 at a time
    short* bst = (short*)&olds[0][0] + w * 4096;   // wave-private 8KB region
    short8 bfr[2][8];
#pragma unroll
    for (int nf = 0; nf < 2; ++nf) {
#pragma unroll
        for (int r = 0; r < 16; ++r) {
            const int g0 = nb * 128 + w * 32 + nf * 16 + r;
            const int g = g0 < N_COLS ? g0 : N_COLS - 1;
            const float4 v = *(const float4*)(W + (size_t)g * H_DIM + 4 * l);
            float am = fmaxf(fmaxf(fabsf(v.x), fabsf(v.y)), fmaxf(fabsf(v.z), fabsf(v.w)));
            am = wave_absmax64(am);                       // row absmax (all lanes)
            const float qsc = QF / ((am == 0.f) ? 1.f : am);
            short4v q;
            q.x = f32_to_bf16_exact(rintf(v.x * qsc));    // exactly quant_w's math
            q.y = f32_to_bf16_exact(rintf(v.y * qsc));
            q.z = f32_to_bf16_exact(rintf(v.z * qsc));
            q.w = f32_to_bf16_exact(rintf(v.w * qsc));
            *(short4v*)(bst + r * 256 + ((4 * l) ^ ((r & 7) << 3))) = q;
            if (l == r) smax[w * 32 + nf * 16 + r] = am;
        }
        // frag reads: lane = row lm, cols kk*32+8lg..+7 (swizzle-matched)
#pragma unroll
        for (int kk = 0; kk < 8; ++kk) {
            const int col = (kk * 32 + 8 * lg) ^ ((lm & 7) << 3);
            bfr[nf][kk] = *(const short8*)(bst + lm * 256 + col);
        }
        // drain reads before nf=1 overwrites the region (wave-local WAR)
        asm volatile("s_waitcnt lgkmcnt(0)" ::: "memory");
        __builtin_amdgcn_sched_barrier(0);
    }
    sync_lds();   // cross-wave: stage region becomes olds; smax visible to all

    // store-side per-lane constants
    const int colb = nb * 128 + 2 * l;
    const bool okc = colb < N_COLS;        // N even -> float2 fully in/out
    const int colc = okc ? colb : 0;
    const f32x2 sw2 = *(const f32x2*)(smax + 2 * l);   // ds_read, loop-invariant
    const f32x2 b2  = *(const f32x2*)(bias + colc);

    const int tile0 = tbase >> 5;
    short8 acur[8], anxt[8];
#pragma unroll
    for (int kk = 0; kk < 8; ++kk)
        acur[kk] = *(const short8*)(x8F + (size_t)((tile0 * 8 + kk) * 2 + 0) * 512 + l * 8);

#pragma unroll 1
    for (int ii = 0; ii < 8; ++ii) {
        const int tile = tile0 + ii;
        f32x4 acc[2][2];
#pragma unroll
        for (int mr = 0; mr < 2; ++mr)
#pragma unroll
            for (int nf = 0; nf < 2; ++nf) acc[mr][nf] = (f32x4){0.f, 0.f, 0.f, 0.f};

        // ---- mr = 0: prefetch mr=1 frags, then MFMA on acur
#pragma unroll
        for (int kk = 0; kk < 8; ++kk)
            anxt[kk] = *(const short8*)(x8F + (size_t)((tile * 8 + kk) * 2 + 1) * 512 + l * 8);
#pragma unroll
        for (int kk = 0; kk < 8; ++kk) {
            acc[0][0] = __builtin_amdgcn_mfma_f32_16x16x32_bf16(bfr[0][kk], acur[kk], acc[0][0], 0, 0, 0);
            acc[0][1] = __builtin_amdgcn_mfma_f32_16x16x32_bf16(bfr[1][kk], acur[kk], acc[0][1], 0, 0, 0);
        }

        // ---- mr = 1: prefetch next iter's mr=0 frags, then MFMA on anxt
        if (ii < 7) {
#pragma unroll
            for (int kk = 0; kk < 8; ++kk)
                acur[kk] = *(const short8*)(x8F + (size_t)(((tile + 1) * 8 + kk) * 2 + 0) * 512 + l * 8);
        }
#pragma unroll
        for (int kk = 0; kk < 8; ++kk) {
            acc[1][0] = __builtin_amdgcn_mfma_f32_16x16x32_bf16(bfr[0][kk], anxt[kk], acc[1][0], 0, 0, 0);
            acc[1][1] = __builtin_amdgcn_mfma_f32_16x16x32_bf16(bfr[1][kk], anxt[kk], acc[1][1], 0, 0, 0);
        }

        // raw acc -> LDS, XOR-swizzled cols
        // D[n][t]: t = mr*16 + lm, n = w*32 + nf*16 + lg*4 + r
        float* ob = olds[ii & 1];
#pragma unroll
        for (int mr = 0; mr < 2; ++mr) {
            const int trow = mr * 16 + lm;
#pragma unroll
            for (int nf = 0; nf < 2; ++nf) {
                const int c = (w * 32 + nf * 16 + lg * 4) ^ ((trow & 7) << 2);
                *(f32x4*)(ob + trow * 128 + c) = acc[mr][nf];
            }
        }
        sync_lds();   // lgkmcnt(0) + raw s_barrier — NO vmcnt drain

        // store phase: per row one 512B unit-stride f32x2 segment; dequant on
        // read; NONTEMPORAL full-line no-allocate writes (validated R13).
        const int t0 = tbase + ii * 32;
#pragma unroll
        for (int i = 0; i < 8; ++i) {
            const int row = w * 8 + i;
            const int t = t0 + row;
            const float s0 = sx[t] * invqq;                  // wave-uniform
            const f32x2 v = *(const f32x2*)(ob + row * 128 + ((2 * l) ^ ((row & 7) << 2)));
            if (okc) {
                f32x2 o;
                o[0] = v[0] * (s0 * sw2[0]) + b2[0];
                o[1] = v[1] * (s0 * sw2[1]) + b2[1];
                __builtin_nontemporal_store(o, (f32x2*)(out + (size_t)t * N_COLS + colb));
            }
        }
    }
}

extern "C" void kernel_launch(void* const* d_in, const int* in_sizes, int n_in,
                              void* d_out, int out_size, void* d_ws, size_t ws_size,
                              hipStream_t stream) {
    const float* X    = (const float*)d_in[0];   // [8,128,256] f32
    const float* W    = (const float*)d_in[1];   // [100000,256] f32
    const float* bias = (const float*)d_in[2];   // [100000] f32
    float* out = (float*)d_out;                  // [1024,100000] f32

    // ws layout: x8F 512KB | sx 4KB   (w8F/sw no longer needed)
    const size_t x8_bytes = (size_t)T_ROWS * H_DIM * 2;

    short* x8F = (short*)d_ws;
    float* sx  = (float*)((char*)d_ws + x8_bytes);

    quant_x<<<T_ROWS / 4, 256, 0, stream>>>(X, x8F, sx);
    gemm_fused<<<GRID3, 256, 0, stream>>>(x8F, sx, W, bias, out);
}

// Round 18
// 122.625 us; speedup vs baseline: 1.3795x; 1.3795x over previous
//
#include <hip/hip_runtime.h>

// Problem constants (from reference): H=256, N=100000, B=8, S=128 -> T=1024
#define T_ROWS 1024
#define H_DIM  256
#define N_COLS 100000
#define QF     127.0f

#define NB16   6250                // N/16 (exact)
#define NB3    782                 // ceil(N/128), last block 32 cols
#define TCH    4                   // t-chunks of 256
#define GRID3  (NB3 * TCH)         // 3128 = 8*391 -> bijective XCD swizzle
#define QGRID  (NB16 + T_ROWS / 4) // merged quantize grid: 6250 W + 256 X blocks

typedef __attribute__((ext_vector_type(4))) float f32x4;
typedef __attribute__((ext_vector_type(2))) float f32x2;
typedef __attribute__((ext_vector_type(8))) short short8;   // 8 bf16 (MFMA frag)
typedef __attribute__((ext_vector_type(4))) short short4v;  // 4 bf16 = 8B

// Exact f32 -> bf16 for integer-valued floats |q| <= 127: truncation is exact.
__device__ __forceinline__ short f32_to_bf16_exact(float f) {
    unsigned u = __builtin_bit_cast(unsigned, f);
    return (short)(u >> 16);
}

__device__ __forceinline__ float wave_absmax64(float v) {
#pragma unroll
    for (int off = 32; off > 0; off >>= 1)
        v = fmaxf(v, __shfl_xor(v, off, 64));
    return v;
}

// Raw LDS-only barrier: NO vmcnt drain (global stores stay in flight).
// Validated passing in R9/R10/R12/R13/R16.
__device__ __forceinline__ void sync_lds() {
    asm volatile("s_waitcnt lgkmcnt(0)" ::: "memory");
    __builtin_amdgcn_s_barrier();
    __builtin_amdgcn_sched_barrier(0);
}

// ---------------- Kernel 1: MERGED quantize (X and W in one dispatch)
// Blocks [0, NB16): quant_w body verbatim (16 W rows -> frag-major w8F + sw).
// Blocks [NB16, QGRID): quant_x body verbatim (4 X rows -> frag-major x8F + sx).
// Both are independent; merging removes one kernel-launch boundary.
__global__ __launch_bounds__(256) void quant_xw(const float* __restrict__ X,
                                                const float* __restrict__ W,
                                                short* __restrict__ x8F,
                                                float* __restrict__ sx,
                                                short* __restrict__ w8F,
                                                float* __restrict__ sw) {
    if (blockIdx.x < NB16) {
        // ---- quant_w body: w8F layout [nb16][kk(8)][lane(64)][j(8)] shorts
        __shared__ short tile[16 * 256];
        const int tid = threadIdx.x;
        const int nb16 = blockIdx.x;                 // 0..6249
        const int r16 = tid >> 4, c16 = tid & 15;
        const int n = nb16 * 16 + r16;
        const float4* src = (const float4*)(W + (size_t)n * H_DIM + c16 * 16);
        float4 v[4];
        float amax = 0.f;
#pragma unroll
        for (int i = 0; i < 4; ++i) {
            v[i] = src[i];
            amax = fmaxf(amax, fmaxf(fmaxf(fabsf(v[i].x), fabsf(v[i].y)),
                                     fmaxf(fabsf(v[i].z), fabsf(v[i].w))));
        }
#pragma unroll
        for (int off = 8; off > 0; off >>= 1)
            amax = fmaxf(amax, __shfl_xor(amax, off, 64));
        const float scale = (amax == 0.f) ? 1.f : amax;
        const float qs = QF / scale;
        short qv[16];
#pragma unroll
        for (int i = 0; i < 4; ++i) {
            qv[i * 4 + 0] = f32_to_bf16_exact(rintf(v[i].x * qs));
            qv[i * 4 + 1] = f32_to_bf16_exact(rintf(v[i].y * qs));
            qv[i * 4 + 2] = f32_to_bf16_exact(rintf(v[i].z * qs));
            qv[i * 4 + 3] = f32_to_bf16_exact(rintf(v[i].w * qs));
        }
        *(short8*)&tile[r16 * 256 + c16 * 16]     = *(short8*)&qv[0];
        *(short8*)&tile[r16 * 256 + c16 * 16 + 8] = *(short8*)&qv[8];
        if (c16 == 0) sw[n] = amax;
        __syncthreads();
        const int kk = tid >> 5, i2 = tid & 31;
        const int L0 = 2 * i2, L1 = L0 + 1;
        short* dst = w8F + ((size_t)nb16 * 8 + kk) * 512 + i2 * 16;
        *(short8*)(dst)     = *(short8*)&tile[(L0 & 15) * 256 + kk * 32 + (L0 >> 4) * 8];
        *(short8*)(dst + 8) = *(short8*)&tile[(L1 & 15) * 256 + kk * 32 + (L1 >> 4) * 8];
    } else {
        // ---- quant_x body: x8F layout [tile(32)][kk(8)][mr(2)][lane(64)][j(8)]
        const int bidx = blockIdx.x - NB16;          // 0..255
        const int w = threadIdx.x >> 6, l = threadIdx.x & 63;
        const int row = bidx * 4 + w;                // t
        const float4 v = ((const float4*)X)[row * 64 + l];
        float amax = fmaxf(fmaxf(fabsf(v.x), fabsf(v.y)), fmaxf(fabsf(v.z), fabsf(v.w)));
        amax = wave_absmax64(amax);
        const float scale = (amax == 0.f) ? 1.f : amax;
        const float qs = QF / scale;
        short4v q;
        q.x = f32_to_bf16_exact(rintf(v.x * qs));
        q.y = f32_to_bf16_exact(rintf(v.y * qs));
        q.z = f32_to_bf16_exact(rintf(v.z * qs));
        q.w = f32_to_bf16_exact(rintf(v.w * qs));
        const int tile = row >> 5, mr = (row >> 4) & 1, lm = row & 15;
        const int kk = l >> 3, lg = (l >> 1) & 3, j = (l & 1) * 4;
        const int lane = lg * 16 + lm;
        *(short4v*)(x8F + (((tile * 8 + kk) * 2 + mr) * 64 + lane) * 8 + j) = q;
        if (l == 0) sx[row] = amax;
    }
}

// ---------------- Kernel 2: contiguous-VMEM GEMM (R13 configuration, verbatim)
// Proven optimum of this structure (127.5µs total, reproduced R16): 3
// blocks/CU keeps the shared 512KB x8F panel L2/L3-resident (4/CU thrashed,
// R15; 5/CU spilled, R14); per-inst unit-stride frag loads (R7); lgkm-only
// barrier, no vmcnt drain (R9); NONTEMPORAL full-line output stores (R13).
__global__ __launch_bounds__(256, 3) void gemm_ctg(const short* __restrict__ x8F,
                                                   const float* __restrict__ sx,
                                                   const short* __restrict__ w8F,
                                                   const float* __restrict__ sw,
                                                   const float* __restrict__ bias,
                                                   float* __restrict__ out) {
    __shared__ float olds[2][32 * 128];   // 2 x 16KB

    // bijective XCD swizzle (3128 = 8*391); tc-inner -> w8 panel L2 reuse
    const int bid = blockIdx.x;
    const int s = (bid & 7) * (GRID3 / 8) + (bid >> 3);
    const int nb = s >> 2;                 // 0..781
    const int tc = s & 3;                  // t-chunk of 256 rows
    const int w = threadIdx.x >> 6, l = threadIdx.x & 63;
    const int lg = l >> 4, lm = l & 15;
    const int tbase = tc * 256;
    const int nb16w = nb * 8 + w * 2;      // this wave's first 16-row n-block

    // B-frags: 16 x 1KB contiguous loads, persist in regs across all 8 iters
    short8 bfr[2][8];
#pragma unroll
    for (int nf = 0; nf < 2; ++nf) {
        const int nbc = (nb16w + nf < NB16) ? (nb16w + nf) : (NB16 - 1);
        const short* B = w8F + (size_t)nbc * 4096 + l * 8;
#pragma unroll
        for (int kk = 0; kk < 8; ++kk)
            bfr[nf][kk] = *(const short8*)(B + kk * 512);
    }

    // store-side per-lane constants: this lane stores cols colb, colb+1
    const int colb = nb * 128 + 2 * l;
    const bool okc = colb < N_COLS;        // N even -> float2 fully in/out
    const int colc = okc ? colb : 0;
    const f32x2 sw2 = *(const f32x2*)(sw + colc);
    const f32x2 b2  = *(const f32x2*)(bias + colc);
    const float invqq = 1.0f / (QF * QF);

    const int tile0 = tbase >> 5;
    short8 acur[8], anxt[8];
    // preload (ii=0, mr=0)
#pragma unroll
    for (int kk = 0; kk < 8; ++kk)
        acur[kk] = *(const short8*)(x8F + (size_t)((tile0 * 8 + kk) * 2 + 0) * 512 + l * 8);

#pragma unroll 1
    for (int ii = 0; ii < 8; ++ii) {
        const int tile = tile0 + ii;
        f32x4 acc[2][2];
#pragma unroll
        for (int mr = 0; mr < 2; ++mr)
#pragma unroll
            for (int nf = 0; nf < 2; ++nf) acc[mr][nf] = (f32x4){0.f, 0.f, 0.f, 0.f};

        // ---- mr = 0: prefetch mr=1 frags, then MFMA on acur
#pragma unroll
        for (int kk = 0; kk < 8; ++kk)
            anxt[kk] = *(const short8*)(x8F + (size_t)((tile * 8 + kk) * 2 + 1) * 512 + l * 8);
#pragma unroll
        for (int kk = 0; kk < 8; ++kk) {
            acc[0][0] = __builtin_amdgcn_mfma_f32_16x16x32_bf16(bfr[0][kk], acur[kk], acc[0][0], 0, 0, 0);
            acc[0][1] = __builtin_amdgcn_mfma_f32_16x16x32_bf16(bfr[1][kk], acur[kk], acc[0][1], 0, 0, 0);
        }

        // ---- mr = 1: prefetch next iter's mr=0 frags, then MFMA on anxt
        if (ii < 7) {
#pragma unroll
            for (int kk = 0; kk < 8; ++kk)
                acur[kk] = *(const short8*)(x8F + (size_t)(((tile + 1) * 8 + kk) * 2 + 0) * 512 + l * 8);
        }
#pragma unroll
        for (int kk = 0; kk < 8; ++kk) {
            acc[1][0] = __builtin_amdgcn_mfma_f32_16x16x32_bf16(bfr[0][kk], anxt[kk], acc[1][0], 0, 0, 0);
            acc[1][1] = __builtin_amdgcn_mfma_f32_16x16x32_bf16(bfr[1][kk], anxt[kk], acc[1][1], 0, 0, 0);
        }

        // raw acc -> LDS, XOR-swizzled cols (bank spread)
        // D[n][t]: t = mr*16 + lm, n = w*32 + nf*16 + lg*4 + r
        float* ob = olds[ii & 1];
#pragma unroll
        for (int mr = 0; mr < 2; ++mr) {
            const int trow = mr * 16 + lm;
#pragma unroll
            for (int nf = 0; nf < 2; ++nf) {
                const int c = (w * 32 + nf * 16 + lg * 4) ^ ((trow & 7) << 2);
                *(f32x4*)(ob + trow * 128 + c) = acc[mr][nf];
            }
        }
        sync_lds();   // lgkmcnt(0) + raw s_barrier — NO vmcnt drain

        // store phase: wave w stores rows w*8..w*8+7; per row one 512B
        // unit-stride segment (64 lanes x float2), dequant on read.
        // NONTEMPORAL full-line no-allocate writes (validated R13).
        const int t0 = tbase + ii * 32;
#pragma unroll
        for (int i = 0; i < 8; ++i) {
            const int row = w * 8 + i;
            const int t = t0 + row;
            const float s0 = sx[t] * invqq;                  // wave-uniform
            const f32x2 v = *(const f32x2*)(ob + row * 128 + ((2 * l) ^ ((row & 7) << 2)));
            if (okc) {
                f32x2 o;
                o[0] = v[0] * (s0 * sw2[0]) + b2[0];
                o[1] = v[1] * (s0 * sw2[1]) + b2[1];
                __builtin_nontemporal_store(o, (f32x2*)(out + (size_t)t * N_COLS + colb));
            }
        }
        // dbuf + next iter's sync_lds protect this buffer until reads land
    }
}

extern "C" void kernel_launch(void* const* d_in, const int* in_sizes, int n_in,
                              void* d_out, int out_size, void* d_ws, size_t ws_size,
                              hipStream_t stream) {
    const float* X    = (const float*)d_in[0];   // [8,128,256] f32
    const float* W    = (const float*)d_in[1];   // [100000,256] f32
    const float* bias = (const float*)d_in[2];   // [100000] f32
    float* out = (float*)d_out;                  // [1024,100000] f32

    // ws layout: x8F 512KB | sx 4KB | w8F 51.2MB | sw 400KB (fits)
    const size_t x8_bytes = (size_t)T_ROWS * H_DIM * 2;
    const size_t sx_bytes = (size_t)T_ROWS * 4;
    const size_t w8_bytes = (size_t)N_COLS * H_DIM * 2;

    short* x8F = (short*)d_ws;
    float* sx  = (float*)((char*)d_ws + x8_bytes);
    short* w8F = (short*)((char*)d_ws + x8_bytes + sx_bytes);
    float* sw  = (float*)((char*)d_ws + x8_bytes + sx_bytes + w8_bytes);

    quant_xw<<<QGRID, 256, 0, stream>>>(X, W, x8F, sx, w8F, sw);
    gemm_ctg<<<GRID3, 256, 0, stream>>>(x8F, sx, w8F, sw, bias, out);
}